// Round 1
// baseline (2518.332 us; speedup 1.0000x reference)
//
#include <hip/hip_runtime.h>
#include <hip/hip_bf16.h>
#include <cstdint>
#include <cstddef>

typedef unsigned short u16;
typedef __attribute__((ext_vector_type(4))) float f32x4;
typedef __attribute__((ext_vector_type(8))) short bf16x8;
typedef __attribute__((ext_vector_type(8))) unsigned short u16x8;
typedef __attribute__((ext_vector_type(4))) unsigned short u16x4;

#define D_LAYERS 8
#define DIMN 1024
#define FFD 4096
#define VOCAB 32000
#define MROWS 4096   /* B*S */
#define SEQ 2048
#define NCHUNK 64
#define LCHUNK 32

// ---------- helpers ----------
__device__ __forceinline__ u16 f2b(float f) {
  union { float f; unsigned u; } v; v.f = f;
  unsigned r = v.u + 0x7FFFu + ((v.u >> 16) & 1u);
  return (u16)(r >> 16);
}
__device__ __forceinline__ float b2f(u16 h) {
  union { unsigned u; float f; } v; v.u = ((unsigned)h) << 16;
  return v.f;
}
__device__ __forceinline__ float sigm(float x) { return 1.f / (1.f + __expf(-x)); }

// async global->LDS, 16B per lane. LDS dest is wave-uniform base + lane*16 (HW).
__device__ __forceinline__ void async16(const void* g, void* l) {
  auto gp = reinterpret_cast<const __attribute__((address_space(1))) char*>(
      reinterpret_cast<uintptr_t>(g));
  auto lp = reinterpret_cast<__attribute__((address_space(3))) char*>(
      reinterpret_cast<uintptr_t>(l));
  __builtin_amdgcn_global_load_lds(gp, lp, 16, 0, 0);
}

__device__ __forceinline__ float blk_sum(float v) {
  __shared__ float sm[4];
  #pragma unroll
  for (int o = 32; o > 0; o >>= 1) v += __shfl_xor(v, o);
  if ((threadIdx.x & 63) == 0) sm[threadIdx.x >> 6] = v;
  __syncthreads();
  float r = sm[0] + sm[1] + sm[2] + sm[3];
  __syncthreads();
  return r;
}

// ---------- small kernels ----------
__global__ __launch_bounds__(256) void k_cvt(const f32x4* __restrict__ in,
                                             u16x8* __restrict__ out) {
  size_t i = (size_t)blockIdx.x * 256 + threadIdx.x;
  f32x4 a = in[i * 2], b = in[i * 2 + 1];
  u16x8 o;
  o[0] = f2b(a[0]); o[1] = f2b(a[1]); o[2] = f2b(a[2]); o[3] = f2b(a[3]);
  o[4] = f2b(b[0]); o[5] = f2b(b[1]); o[6] = f2b(b[2]); o[7] = f2b(b[3]);
  out[i] = o;
}

__global__ __launch_bounds__(256) void k_embed(const int* __restrict__ tok,
                                               const float* __restrict__ emb,
                                               float* __restrict__ x) {
  const int r = blockIdx.x;
  const int tk = tok[r];
  f32x4 v = ((const f32x4*)(emb + (size_t)tk * DIMN))[threadIdx.x];
  float ss = v[0]*v[0] + v[1]*v[1] + v[2]*v[2] + v[3]*v[3];
  float tot = blk_sum(ss);
  float nrm = sqrtf(tot);
  float s = (nrm > 1.f) ? (1.f / (nrm + 1e-7f)) : 1.f;
  f32x4 o = {v[0]*s, v[1]*s, v[2]*s, v[3]*s};
  ((f32x4*)(x + (size_t)r * DIMN))[threadIdx.x] = o;
}

__global__ __launch_bounds__(256) void k_rms(const float* __restrict__ x,
                                             const float* __restrict__ wgt,
                                             u16* __restrict__ out) {
  const int r = blockIdx.x;
  f32x4 v = ((const f32x4*)(x + (size_t)r * DIMN))[threadIdx.x];
  float ss = v[0]*v[0] + v[1]*v[1] + v[2]*v[2] + v[3]*v[3];
  float tot = blk_sum(ss);
  float sc = rsqrtf(tot * (1.f / DIMN) + 1e-6f);
  f32x4 w = ((const f32x4*)wgt)[threadIdx.x];
  u16x4 o;
  o[0] = f2b(v[0] * sc * w[0]);
  o[1] = f2b(v[1] * sc * w[1]);
  o[2] = f2b(v[2] * sc * w[2]);
  o[3] = f2b(v[3] * sc * w[3]);
  ((u16x4*)(out + (size_t)r * DIMN))[threadIdx.x] = o;
}

// scan phase A: per-chunk aggregates (A = prod f, V = chunk-local scan end)
__global__ __launch_bounds__(256) void k_scanA(const float* __restrict__ f,
                                               const float* __restrict__ ti,
                                               const float* __restrict__ gg,
                                               float* __restrict__ Ac,
                                               float* __restrict__ Vc) {
  const int bx = blockIdx.x;              // b*256 + c*4 + dg
  const int dg = bx & 3, c = (bx >> 2) & 63, b = bx >> 8;
  const int d = dg * 256 + threadIdx.x;
  const size_t base = ((size_t)(b * SEQ + c * LCHUNK)) * DIMN + d;
  float a = 1.f, h = 0.f;
  #pragma unroll 4
  for (int t = 0; t < LCHUNK; ++t) {
    size_t ix = base + (size_t)t * DIMN;
    float fv = f[ix];
    float vv = ti[ix] * gg[ix];
    h = fv * h + vv;
    a *= fv;
  }
  const size_t ci = ((size_t)(b * NCHUNK + c)) * DIMN + d;
  Ac[ci] = a; Vc[ci] = h;
}

// scan phase B: exclusive scan over chunks, init = h0
__global__ __launch_bounds__(256) void k_scanB(const float* __restrict__ Ac,
                                               const float* __restrict__ Vc,
                                               const float* __restrict__ h0,
                                               float* __restrict__ carry) {
  const int idx = blockIdx.x * 256 + threadIdx.x;  // 0..2047
  const int b = idx >> 10, d = idx & 1023;
  float h = h0[d];
  for (int c = 0; c < NCHUNK; ++c) {
    size_t ci = ((size_t)(b * NCHUNK + c)) * DIMN + d;
    carry[ci] = h;
    h = Ac[ci] * h + Vc[ci];
  }
}

// scan phase C: recompute with carry-in, y = tanh(h)*sig(og), x += y
__global__ __launch_bounds__(256) void k_scanC(const float* __restrict__ f,
                                               const float* __restrict__ ti,
                                               const float* __restrict__ gg,
                                               const float* __restrict__ oo,
                                               const float* __restrict__ carry,
                                               float* __restrict__ x) {
  const int bx = blockIdx.x;
  const int dg = bx & 3, c = (bx >> 2) & 63, b = bx >> 8;
  const int d = dg * 256 + threadIdx.x;
  const size_t base = ((size_t)(b * SEQ + c * LCHUNK)) * DIMN + d;
  float h = carry[((size_t)(b * NCHUNK + c)) * DIMN + d];
  for (int t = 0; t < LCHUNK; ++t) {
    size_t ix = base + (size_t)t * DIMN;
    float fv = f[ix];
    h = fv * h + ti[ix] * gg[ix];
    float y = tanhf(h) * oo[ix];
    x[ix] += y;
  }
}

// ---------- GEMM: C = A[M,K] @ B[N,K]^T (+bias, epilogue) ----------
constexpr int EPI_GATES = 0, EPI_SILU_BF = 1, EPI_MUL_BF = 2, EPI_RES_F32 = 3,
              EPI_BIAS_F32 = 4;

template<int BN_T, int EPI>
__global__ __launch_bounds__(256, 2)
void gemm_bt(const u16* __restrict__ A,
             const u16* __restrict__ B0, const u16* __restrict__ B1,
             const u16* __restrict__ B2, const u16* __restrict__ B3,
             const float* __restrict__ bias0, const float* __restrict__ bias1,
             const float* __restrict__ bias2, const float* __restrict__ bias3,
             float* __restrict__ oF0, float* __restrict__ oF1,
             float* __restrict__ oF2, float* __restrict__ oF3,
             u16* __restrict__ oB,
             const u16* __restrict__ exB, const float* __restrict__ exF,
             int N, int K)
{
  constexpr int MF = (BN_T == 128) ? 4 : 2;       // 16-row frags per wave (M)
  constexpr int WAVES_N = (BN_T == 128) ? 2 : 1;
  constexpr int ISS_B = BN_T / 32;                // global_load_lds issues for B
  __shared__ __align__(16) u16 As[128 * 64];
  __shared__ __align__(16) u16 Bs[BN_T * 64];
  const int tid = threadIdx.x;
  const int w = tid >> 6, lane = tid & 63;
  const int wm = w / WAVES_N, wn = w % WAVES_N;
  const int m0 = blockIdx.x * 128;
  const int n0 = blockIdx.y * BN_T;
  const int z = blockIdx.z;

  const u16* Bw;
  const float* bias;
  float* oF;
  if constexpr (EPI == EPI_GATES) {
    Bw   = (z == 0) ? B0 : (z == 1) ? B1 : (z == 2) ? B2 : B3;
    bias = (z == 0) ? bias0 : (z == 1) ? bias1 : (z == 2) ? bias2 : bias3;
    oF   = (z == 0) ? oF0 : (z == 1) ? oF1 : (z == 2) ? oF2 : oF3;
  } else {
    Bw = B0; bias = bias0; oF = oF0;
  }

  const f32x4 zero = {0.f, 0.f, 0.f, 0.f};
  f32x4 acc[MF][4];
  #pragma unroll
  for (int mf = 0; mf < MF; ++mf)
    #pragma unroll
    for (int nf = 0; nf < 4; ++nf) acc[mf][nf] = zero;

  for (int kt = 0; kt < K; kt += 64) {
    // stage A (128x64 bf16 = 16KB) with pre-swizzled source (rule #21)
    #pragma unroll
    for (int i = 0; i < 4; ++i) {
      int p = i * 4096 + w * 1024 + lane * 16;   // linear LDS byte
      int r = p >> 7;
      int cs = (p & 127) ^ ((r & 7) << 4);       // inverse-swizzled src col
      async16(A + ((size_t)(m0 + r) * K + kt) + (cs >> 1),
              (char*)As + i * 4096 + w * 1024);
    }
    #pragma unroll
    for (int i = 0; i < ISS_B; ++i) {
      int p = i * 4096 + w * 1024 + lane * 16;
      int r = p >> 7;
      int cs = (p & 127) ^ ((r & 7) << 4);
      async16(Bw + ((size_t)(n0 + r) * K + kt) + (cs >> 1),
              (char*)Bs + i * 4096 + w * 1024);
    }
    __syncthreads();   // compiler drains vmcnt before barrier
    #pragma unroll
    for (int ks = 0; ks < 2; ++ks) {
      bf16x8 av[MF], bv[4];
      const int cbase = ks * 64 + ((lane >> 4) << 4);
      #pragma unroll
      for (int mf = 0; mf < MF; ++mf) {
        int r = wm * (MF * 16) + mf * 16 + (lane & 15);
        av[mf] = *(const bf16x8*)((const char*)As + r * 128 + (cbase ^ ((r & 7) << 4)));
      }
      #pragma unroll
      for (int nf = 0; nf < 4; ++nf) {
        int r = wn * 64 + nf * 16 + (lane & 15);
        bv[nf] = *(const bf16x8*)((const char*)Bs + r * 128 + (cbase ^ ((r & 7) << 4)));
      }
      #pragma unroll
      for (int mf = 0; mf < MF; ++mf)
        #pragma unroll
        for (int nf = 0; nf < 4; ++nf)
          acc[mf][nf] = __builtin_amdgcn_mfma_f32_16x16x32_bf16(
              av[mf], bv[nf], acc[mf][nf], 0, 0, 0);
    }
    __syncthreads();
  }

  // epilogue: C/D map col=lane&15, row=(lane>>4)*4+j
  #pragma unroll
  for (int nf = 0; nf < 4; ++nf) {
    const int n = n0 + wn * 64 + nf * 16 + (lane & 15);
    const float bb = bias[n];
    #pragma unroll
    for (int mf = 0; mf < MF; ++mf) {
      #pragma unroll
      for (int j = 0; j < 4; ++j) {
        const int m = m0 + wm * (MF * 16) + mf * 16 + ((lane >> 4) << 2) + j;
        const size_t idx = (size_t)m * N + n;
        float v = acc[mf][nf][j] + bb;
        if constexpr (EPI == EPI_GATES) {
          oF[idx] = (z == 1) ? tanhf(v) : sigm(v);
        } else if constexpr (EPI == EPI_SILU_BF) {
          oB[idx] = f2b(v * sigm(v));
        } else if constexpr (EPI == EPI_MUL_BF) {
          oB[idx] = f2b(v * b2f(exB[idx]));
        } else if constexpr (EPI == EPI_RES_F32) {
          oF[idx] = v + exF[idx];
        } else {
          oF[idx] = v;
        }
      }
    }
  }
}

// ---------- launcher ----------
extern "C" void kernel_launch(void* const* d_in, const int* in_sizes, int n_in,
                              void* d_out, int out_size, void* d_ws, size_t ws_size,
                              hipStream_t stream) {
  (void)in_sizes; (void)n_in; (void)out_size; (void)ws_size;
  const int*   tokens = (const int*)d_in[0];
  const float* emb  = (const float*)d_in[1];
  const float* h0   = (const float*)d_in[2];
  const float* Wf   = (const float*)d_in[3];
  const float* bf_  = (const float*)d_in[4];
  const float* Wi   = (const float*)d_in[5];
  const float* bi_  = (const float*)d_in[6];
  const float* Wig  = (const float*)d_in[7];
  const float* big_ = (const float*)d_in[8];
  const float* Wog  = (const float*)d_in[9];
  const float* bog_ = (const float*)d_in[10];
  const float* n1   = (const float*)d_in[11];
  const float* n2   = (const float*)d_in[12];
  const float* Wfc  = (const float*)d_in[13];
  const float* bfc_ = (const float*)d_in[14];
  const float* Wfa  = (const float*)d_in[15];
  const float* bfa_ = (const float*)d_in[16];
  const float* Wfo  = (const float*)d_in[17];
  const float* bfo_ = (const float*)d_in[18];
  const float* nl_  = (const float*)d_in[19];
  const float* Wout = (const float*)d_in[20];
  const float* bout_= (const float*)d_in[21];
  float* out = (float*)d_out;

  char* p = (char*)d_ws;
  auto alloc = [&](size_t bytes) {
    char* r = p; p += (bytes + 255) & ~(size_t)255; return r;
  };
  u16* wbWf   = (u16*)alloc((size_t)DIMN * DIMN * 2);
  u16* wbWi   = (u16*)alloc((size_t)DIMN * DIMN * 2);
  u16* wbWig  = (u16*)alloc((size_t)DIMN * DIMN * 2);
  u16* wbWog  = (u16*)alloc((size_t)DIMN * DIMN * 2);
  u16* wbWfc  = (u16*)alloc((size_t)FFD * DIMN * 2);
  u16* wbWfa  = (u16*)alloc((size_t)FFD * DIMN * 2);
  u16* wbWfo  = (u16*)alloc((size_t)FFD * DIMN * 2);
  u16* wbWout = (u16*)alloc((size_t)VOCAB * DIMN * 2);
  float* x    = (float*)alloc((size_t)MROWS * DIMN * 4);
  u16* hin    = (u16*)alloc((size_t)MROWS * DIMN * 2);
  float* fbuf = (float*)alloc((size_t)MROWS * DIMN * 4);
  float* tibuf= (float*)alloc((size_t)MROWS * DIMN * 4);
  float* ggbuf= (float*)alloc((size_t)MROWS * DIMN * 4);
  float* oobuf= (float*)alloc((size_t)MROWS * DIMN * 4);
  // FFN intermediates alias the (then-dead) gate buffers:
  u16* sa = (u16*)fbuf;                                   // [4096,4096] bf16
  u16* ub = (u16*)((char*)fbuf + (size_t)MROWS * FFD * 2);// [4096,4096] bf16
  float* Ac    = (float*)alloc((size_t)2 * NCHUNK * DIMN * 4);
  float* Vc    = (float*)alloc((size_t)2 * NCHUNK * DIMN * 4);
  float* carry = (float*)alloc((size_t)2 * NCHUNK * DIMN * 4);

  auto cvt = [&](const float* src, u16* dst, size_t nelem) {
    k_cvt<<<dim3((unsigned)(nelem / 2048)), dim3(256), 0, stream>>>(
        (const f32x4*)src, (u16x8*)dst);
  };

  k_embed<<<dim3(MROWS), dim3(256), 0, stream>>>(tokens, emb, x);

  for (int L = 0; L < D_LAYERS; ++L) {
    const size_t oDD = (size_t)L * DIMN * DIMN;
    const size_t oFD = (size_t)L * FFD * DIMN;
    cvt(Wf  + oDD, wbWf,  (size_t)DIMN * DIMN);
    cvt(Wi  + oDD, wbWi,  (size_t)DIMN * DIMN);
    cvt(Wig + oDD, wbWig, (size_t)DIMN * DIMN);
    cvt(Wog + oDD, wbWog, (size_t)DIMN * DIMN);
    cvt(Wfc + oFD, wbWfc, (size_t)FFD * DIMN);
    cvt(Wfa + oFD, wbWfa, (size_t)FFD * DIMN);
    cvt(Wfo + oFD, wbWfo, (size_t)FFD * DIMN);

    k_rms<<<dim3(MROWS), dim3(256), 0, stream>>>(x, n1 + (size_t)L * DIMN, hin);

    gemm_bt<128, EPI_GATES><<<dim3(32, 8, 4), dim3(256), 0, stream>>>(
        hin, wbWf, wbWi, wbWig, wbWog,
        bf_ + (size_t)L * DIMN, bi_ + (size_t)L * DIMN,
        big_ + (size_t)L * DIMN, bog_ + (size_t)L * DIMN,
        fbuf, tibuf, ggbuf, oobuf,
        nullptr, nullptr, nullptr, DIMN, DIMN);

    k_scanA<<<dim3(512), dim3(256), 0, stream>>>(fbuf, tibuf, ggbuf, Ac, Vc);
    k_scanB<<<dim3(8), dim3(256), 0, stream>>>(Ac, Vc, h0 + (size_t)L * DIMN, carry);
    k_scanC<<<dim3(512), dim3(256), 0, stream>>>(fbuf, tibuf, ggbuf, oobuf, carry, x);

    k_rms<<<dim3(MROWS), dim3(256), 0, stream>>>(x, n2 + (size_t)L * DIMN, hin);

    gemm_bt<128, EPI_SILU_BF><<<dim3(32, 32, 1), dim3(256), 0, stream>>>(
        hin, wbWfa, nullptr, nullptr, nullptr,
        bfa_ + (size_t)L * FFD, nullptr, nullptr, nullptr,
        nullptr, nullptr, nullptr, nullptr,
        sa, nullptr, nullptr, FFD, DIMN);

    gemm_bt<128, EPI_MUL_BF><<<dim3(32, 32, 1), dim3(256), 0, stream>>>(
        hin, wbWfc, nullptr, nullptr, nullptr,
        bfc_ + (size_t)L * FFD, nullptr, nullptr, nullptr,
        nullptr, nullptr, nullptr, nullptr,
        ub, sa, nullptr, FFD, DIMN);

    gemm_bt<64, EPI_RES_F32><<<dim3(32, 16, 1), dim3(256), 0, stream>>>(
        ub, wbWfo, nullptr, nullptr, nullptr,
        bfo_ + (size_t)L * DIMN, nullptr, nullptr, nullptr,
        x, nullptr, nullptr, nullptr,
        nullptr, nullptr, x, DIMN, FFD);
  }

  cvt(Wout, wbWout, (size_t)VOCAB * DIMN);
  k_rms<<<dim3(MROWS), dim3(256), 0, stream>>>(x, nl_, hin);
  gemm_bt<128, EPI_BIAS_F32><<<dim3(32, 250, 1), dim3(256), 0, stream>>>(
      hin, wbWout, nullptr, nullptr, nullptr,
      bout_, nullptr, nullptr, nullptr,
      out, nullptr, nullptr, nullptr,
      nullptr, nullptr, nullptr, VOCAB, DIMN);
}